// Round 6
// baseline (114.176 us; speedup 1.0000x reference)
//
#include <hip/hip_runtime.h>
#include <math.h>

#define BN 4096
#define FD 512
#define TT 128            // tile dim (rows and cols per block)
#define BK 64             // k-chunk (elements)
#define NK (FD / BK)      // 8 K-steps
#define TB (TT * BK)      // elems per tile buffer (8192)
#define NJT (BN / TT)     // 32 tiles per dim
#define NPAIR (NJT * (NJT + 1) / 2)   // 528 triangular pairs
#define NBLK NPAIR                    // 528 GEMM blocks (128x128 tile each)
#define NPC 128           // S partial slots per row: col 0..63, row 64..127
#define NJR 32            // angle-pass j-ranges
#define JR (BN / NJR)     // 128 j per range
#define NABLK (NJR * (BN / 256))      // 512 angle blocks (fused into k_sim grid)

typedef __attribute__((ext_vector_type(8))) __bf16 bf16x8;
typedef __attribute__((ext_vector_type(4))) float floatx4;
typedef unsigned long long u64;

__device__ __forceinline__ float wred_sum(float v) {
#pragma unroll
  for (int m = 1; m < 64; m <<= 1) v += __shfl_xor(v, m, 64);
  return v;
}

__device__ __forceinline__ float dot4(float4 a, float4 b) {
  return a.x * b.x + a.y * b.y + a.z * b.z + a.w * b.w;
}

// round-to-nearest-even f32 -> bf16
__device__ __forceinline__ unsigned short f2bf(float x) {
  unsigned u = __float_as_uint(x);
  u += 0x7fffu + ((u >> 16) & 1u);
  return (unsigned short)(u >> 16);
}

__device__ __forceinline__ void load16(const void* g, void* l) {
  __builtin_amdgcn_global_load_lds(
      (const __attribute__((address_space(1))) unsigned int*)g,
      (__attribute__((address_space(3))) unsigned int*)l, 16, 0, 0);
}

// order-preserving float->uint map (monotone for all finite floats)
__device__ __forceinline__ unsigned ford(float v) {
  unsigned u = __float_as_uint(v);
  return u ^ (((unsigned)((int)u >> 31)) | 0x80000000u);
}

// DPP row-rotate (within 16-lane row) — VALU-pipe cross-lane.
template <int N>
__device__ __forceinline__ int rori(int x) {
  return __builtin_amdgcn_update_dpp(0, x, 0x120 | N, 0xf, 0xf, true);
}
template <int N>
__device__ __forceinline__ u64 ror16_u64(u64 k) {
  unsigned lo = (unsigned)rori<N>((int)(unsigned)k);
  unsigned hi = (unsigned)rori<N>((int)(unsigned)(k >> 32));
  return ((u64)hi << 32) | lo;
}
__device__ __forceinline__ u64 red16_max_u64(u64 k) {
  u64 o;
  o = ror16_u64<1>(k); k = o > k ? o : k;
  o = ror16_u64<2>(k); k = o > k ? o : k;
  o = ror16_u64<4>(k); k = o > k ? o : k;
  o = ror16_u64<8>(k); k = o > k ? o : k;
  return k;
}

// 64-lane xor-shuffle on u64 (two 32-bit shuffles)
__device__ __forceinline__ u64 sx64(u64 v, int m) {
  unsigned lo = (unsigned)__shfl_xor((int)(unsigned)v, m, 64);
  unsigned hi = (unsigned)__shfl_xor((int)(unsigned)(v >> 32), m, 64);
  return ((u64)hi << 32) | lo;
}

__device__ __forceinline__ u64 umax64(u64 a, u64 b) { return a > b ? a : b; }

// ------- Kernel 1: normalize rows -> bf16 g, recon cosine, packed angles -----
// apk[t] = {ax, ay, az, label_bits} — one 16B load replaces 4 scalar gathers.
__global__ __launch_bounds__(256) void k_prep(const float* __restrict__ f,
                                              const float* __restrict__ fo,
                                              const float* __restrict__ angles,
                                              const int* __restrict__ labels,
                                              unsigned short* __restrict__ gb,
                                              float* __restrict__ rowr,
                                              float4* __restrict__ apk) {
  const int i = blockIdx.x * 4 + (threadIdx.x >> 6);
  const int lane = threadIdx.x & 63;
  const int t = blockIdx.x * 256 + threadIdx.x;
  if (t < BN) {
    float4 q;
    q.x = angles[t * 3 + 0];
    q.y = angles[t * 3 + 1];
    q.z = angles[t * 3 + 2];
    q.w = __uint_as_float((unsigned)labels[t]);   // bit container only
    apk[t] = q;
  }
  const float4* fr = (const float4*)(f + (size_t)i * FD);
  const float4* orr = (const float4*)(fo + (size_t)i * FD);
  float4 x0 = fr[lane], x1 = fr[lane + 64];
  float4 y0 = orr[lane], y1 = orr[lane + 64];
  float sff = dot4(x0, x0) + dot4(x1, x1);
  float sfo = dot4(x0, y0) + dot4(x1, y1);
  float soo = dot4(y0, y0) + dot4(y1, y1);
  sff = wred_sum(sff);
  sfo = wred_sum(sfo);
  soo = wred_sum(soo);
  float nf = sqrtf(sff);
  float inv = 1.0f / nf;
  ushort4* gr = (ushort4*)(gb + (size_t)i * FD);
  ushort4 s0, s1;
  s0.x = f2bf(x0.x * inv); s0.y = f2bf(x0.y * inv);
  s0.z = f2bf(x0.z * inv); s0.w = f2bf(x0.w * inv);
  s1.x = f2bf(x1.x * inv); s1.y = f2bf(x1.y * inv);
  s1.z = f2bf(x1.z * inv); s1.w = f2bf(x1.w * inv);
  gr[lane] = s0;
  gr[lane + 64] = s1;
  if (lane == 0) {
    rowr[i] = sfo / fmaxf(nf * sqrtf(soo), 1e-8f);
  }
}

// ------- Kernel 2: bf16 MFMA g.gT, 128x128 tiles, T3-min pipelined K-loop ---
// Blocks [0, NBLK): 128x128 GEMM, 4 waves in 2x2 (each 64x64 = 4x4 frags).
//   Double-buffered LDS (2x32KB): per K-step, STAGE(t+1) issues into the
//   other buffer BEFORE compute(t); one vmcnt(0)+barrier per step — load
//   latency hides under MFMA instead of a dead pre-compute drain.
//   Diagonal blocks (a==b) skip B staging; B-frags read from As (same layout).
//   Row-part S slot: 64+2b+wc. Col-part S slot: 4a+w (parity wc == (j>>6)&1).
// Blocks [NBLK, NBLK+NABLK): angle pass — lane=row, j-range of 128 in LDS,
//   read wave-uniform (broadcast, conflict-free).
__global__ __launch_bounds__(256, 2) void k_sim(const unsigned short* __restrict__ gb,
                                                const float4* __restrict__ apk,
                                                u64* __restrict__ pkey,
                                                u64* __restrict__ pangP,
                                                u64* __restrict__ pangN) {
  __shared__ __align__(16) unsigned short As[2 * TB];   // 32 KB (2 bufs)
  __shared__ __align__(16) unsigned short Bs[2 * TB];   // 32 KB (2 bufs)
  const int tid = threadIdx.x;

  if (blockIdx.x >= NBLK) {
    // ---------------- angle P/N pass ----------------
    const int q = blockIdx.x - NBLK;
    const int jr = q & (NJR - 1);      // j-range
    const int ib = q >> 5;             // i-block of 256 rows
    const int i = ib * 256 + tid;
    float4* aj = (float4*)As;          // reuse GEMM LDS (2 KB of 64 KB)
    if (tid < JR) aj[tid] = apk[jr * JR + tid];
    __syncthreads();
    float4 me = apk[i];
    const unsigned lib = __float_as_uint(me.w);
    const int j0 = jr * JR;
    u64 keyP = 0, keyNc = 0;
#pragma unroll 4
    for (int jj = 0; jj < JR; jj++) {
      float4 aw = aj[jj];              // wave-uniform address -> LDS broadcast
      int j = j0 + jj;
      float d0 = me.x - aw.x;
      float d1 = me.y - aw.y;
      float d2 = me.z - aw.z;
      float dd = d0 * d0 + d1 * d1 + d2 * d2;
      u64 ddh = (u64)__float_as_uint(dd) << 32;   // dd>=0: bits monotone
      bool same = (__float_as_uint(aw.w) == lib);
      u64 kp = ddh | (unsigned)(~j);
      if (same && j != i && kp > keyP) keyP = kp;
      u64 kn = ~(ddh | (unsigned)j);
      if (!same && kn > keyNc) keyNc = kn;
    }
    pangP[(size_t)jr * BN + i] = keyP;   // coalesced, fully populated
    pangN[(size_t)jr * BN + i] = keyNc;
    return;
  }

  // ---------------- GEMM + S epilogue (128x128 tile) ----------------
  int a = 0, rem = blockIdx.x;
#pragma unroll 1
  while (rem >= NJT - a) { rem -= NJT - a; a++; }
  const int b = a + rem;
  const int i0 = a * TT;
  const int j0 = b * TT;
  const bool diag = (a == b);

  const int w = tid >> 6;
  const int lane = tid & 63;
  const int wr = w >> 1;            // wave row (0..1): rows wr*64..+63
  const int wc = w & 1;             // wave col (0..1): cols wc*64..+63

  floatx4 acc[4][4];
#pragma unroll
  for (int u = 0; u < 4; u++)
#pragma unroll
    for (int v = 0; v < 4; v++) acc[u][v] = (floatx4){0.f, 0.f, 0.f, 0.f};

  // Staging: position p = tid + 256c holds row p>>3, logical chunk (p&7)^((p>>3)&7).
  const int rp = tid >> 3;                          // 0..31
  const int q8 = ((tid & 7) ^ (rp & 7)) * 8;        // global chunk offset (elems)
  const unsigned short* gA[4];
  const unsigned short* gB[4];
  unsigned short* lA[4];
  unsigned short* lB[4];
#pragma unroll
  for (int c = 0; c < 4; c++) {
    gA[c] = gb + (size_t)(i0 + rp + 32 * c) * FD + q8;
    lA[c] = As + (tid + 256 * c) * 8;
    gB[c] = gb + (size_t)(j0 + rp + 32 * c) * FD + q8;
    lB[c] = Bs + (tid + 256 * c) * 8;
  }

  // Fragment reads: swizzled chunk position q ^ (lane&7).
  const int m = lane & 15;
  const int arow = wr * 64 + m;     // + u*16
  const int brow = wc * 64 + m;     // + v*16
  const int g4 = lane >> 4;
  const int l7 = lane & 7;
  const int koff0 = (g4 ^ l7) * 8;
  const int koff1 = ((4 + g4) ^ l7) * 8;

  // Prologue: stage step 0 into buffer 0.
#pragma unroll
  for (int c = 0; c < 4; c++) load16(gA[c], lA[c]);
  if (!diag) {
#pragma unroll
    for (int c = 0; c < 4; c++) load16(gB[c], lB[c]);
  }
  asm volatile("s_waitcnt vmcnt(0)" ::: "memory");
  __syncthreads();

  for (int t = 0; t < NK; t++) {
    const int cur = (t & 1) * TB;
    // Issue next stage into the other buffer (overlaps with compute below).
    if (t + 1 < NK) {
      const int nxt = ((t + 1) & 1) * TB;
      const int kc = (t + 1) * BK;
#pragma unroll
      for (int c = 0; c < 4; c++) load16(gA[c] + kc, lA[c] + nxt);
      if (!diag) {
#pragma unroll
        for (int c = 0; c < 4; c++) load16(gB[c] + kc, lB[c] + nxt);
      }
    }
    // Compute on current buffer.
    const unsigned short* Ab = As + cur;
    const unsigned short* Bb = (diag ? As : Bs) + cur;
    {
      bf16x8 af[4], bf[4];
#pragma unroll
      for (int u = 0; u < 4; u++)
        af[u] = *(const bf16x8*)(Ab + (arow + u * 16) * BK + koff0);
#pragma unroll
      for (int v = 0; v < 4; v++)
        bf[v] = *(const bf16x8*)(Bb + (brow + v * 16) * BK + koff0);
#pragma unroll
      for (int u = 0; u < 4; u++)
#pragma unroll
        for (int v = 0; v < 4; v++)
          acc[u][v] = __builtin_amdgcn_mfma_f32_16x16x32_bf16(af[u], bf[v], acc[u][v], 0, 0, 0);
#pragma unroll
      for (int u = 0; u < 4; u++)
        af[u] = *(const bf16x8*)(Ab + (arow + u * 16) * BK + koff1);
#pragma unroll
      for (int v = 0; v < 4; v++)
        bf[v] = *(const bf16x8*)(Bb + (brow + v * 16) * BK + koff1);
#pragma unroll
      for (int u = 0; u < 4; u++)
#pragma unroll
        for (int v = 0; v < 4; v++)
          acc[u][v] = __builtin_amdgcn_mfma_f32_16x16x32_bf16(af[u], bf[v], acc[u][v], 0, 0, 0);
    }
    // Per-wave vmcnt(0) + join: after the barrier, ALL waves' stage loads
    // have landed, and no wave still reads the buffer we overwrite next.
    asm volatile("s_waitcnt vmcnt(0)" ::: "memory");
    __syncthreads();
  }

  // Epilogue: C layout col=lane&15, row=quad*4+reg (16x16 family).
  const int quad = lane >> 4;
  const int cx = lane & 15;
  int jc[4];
  unsigned ljb[4];
  float jx[4], jy[4], jz[4];
#pragma unroll
  for (int v = 0; v < 4; v++) {
    jc[v] = j0 + wc * 64 + v * 16 + cx;
    float4 qj = apk[jc[v]];
    jx[v] = qj.x;
    jy[v] = qj.y;
    jz[v] = qj.z;
    ljb[v] = __float_as_uint(qj.w);
  }
  const size_t rbase = (size_t)(64 + 2 * b + wc) * BN;  // row-part slot
  u64 ckey[4] = {0, 0, 0, 0};                           // col-part keys per v
#pragma unroll
  for (int u = 0; u < 4; u++) {
#pragma unroll
    for (int reg = 0; reg < 4; reg++) {
      int i = i0 + wr * 64 + u * 16 + quad * 4 + reg;
      float4 qi = apk[i];
      unsigned lib = __float_as_uint(qi.w);
      u64 rkey = 0;
      unsigned ni = (unsigned)(~i);
#pragma unroll
      for (int v = 0; v < 4; v++) {
        float d0 = qi.x - jx[v];
        float d1 = qi.y - jy[v];
        float d2 = qi.z - jz[v];
        float dd = d0 * d0 + d1 * d1 + d2 * d2;
        bool ok = (lib != ljb[v]) && (dd < 900.0f);   // sqrt(dd)<30
        u64 vh = (u64)ford(acc[u][v][reg]) << 32;
        u64 candR = vh | (unsigned)(~jc[v]);
        if (ok && candR > rkey) rkey = candR;
        u64 candC = vh | ni;
        if (ok && candC > ckey[v]) ckey[v] = candC;
      }
      rkey = red16_max_u64(rkey);
      if (cx == 0) pkey[rbase + i] = rkey;
    }
  }
  if (a != b) {
    // per-wave column argmax over this wave's 64 rows: reduce across quads
    const size_t cbase = (size_t)(4 * a + w) * BN;
#pragma unroll
    for (int v = 0; v < 4; v++) {
      u64 k = ckey[v];
      u64 o = sx64(k, 16); if (o > k) k = o;
      o = sx64(k, 32); if (o > k) k = o;
      if (quad == 0) pkey[cbase + jc[v]] = k;
    }
  }
}

// ------- Kernel 3: per-row finalize — S/P/N partial merges + distances ------
// S col slots for row i (tile t=i>>7): [0,4t) with slot parity (lane&1) ==
// ((i>>6)&1) — other-parity slots were written for the other column half.
// S row slots: [64+2t, 128). P/N: 32 fully-populated partials each.
__global__ __launch_bounds__(256) void k_final(const float* __restrict__ f,
                                               const float4* __restrict__ apk,
                                               const u64* __restrict__ pkey,
                                               const u64* __restrict__ pangP,
                                               const u64* __restrict__ pangN,
                                               float* __restrict__ rowc,
                                               float* __restrict__ rowv) {
  const int i = blockIdx.x * 4 + (threadIdx.x >> 6);
  const int lane = threadIdx.x & 63;
  const int t = i >> 7;
  const int p = (i >> 6) & 1;

  // S partials: two slots per lane with stale-slot masks
  u64 s0 = ((lane < 4 * t) && ((lane & 1) == p)) ? pkey[(size_t)lane * BN + i] : 0;
  u64 s1 = (lane >= 2 * t) ? pkey[(size_t)(64 + lane) * BN + i] : 0;
  u64 keyS = umax64(s0, s1);
  // P/N partials: exactly 32 + 32 across the wave
  u64 keyP = (lane < NJR) ? pangP[(size_t)lane * BN + i] : 0;
  u64 keyNc = (lane >= NJR) ? pangN[(size_t)(lane - NJR) * BN + i] : 0;
#pragma unroll
  for (int off = 1; off < 64; off <<= 1) {
    u64 o = sx64(keyS, off); if (o > keyS) keyS = o;
    o = sx64(keyP, off); if (o > keyP) keyP = o;
    o = sx64(keyNc, off); if (o > keyNc) keyNc = o;
  }
  bool hp = keyP != 0;      // any same-label j != i
  bool hn = keyNc != 0;     // any diff-label j
  if (!(hp && hn)) {
    if (lane == 0) { rowc[i] = 0.0f; rowv[i] = 0.0f; }
    return;
  }
  bool sim_any = keyS != 0;
  int pos = (int)(~(unsigned)keyP);
  u64 keyN = ~keyNc;        // (ddbits<<32 | j) of the min
  int neg = sim_any ? (int)(~(unsigned)keyS) : (int)(unsigned)keyN;

  // triplet distances (reference adds 1e-6 to the per-element difference)
  const float4* fa = (const float4*)(f + (size_t)i * FD);
  const float4* fp = (const float4*)(f + (size_t)pos * FD);
  const float4* fn = (const float4*)(f + (size_t)neg * FD);
  float sp = 0.0f, sn = 0.0f;
#pragma unroll
  for (int t2 = 0; t2 < 2; t2++) {
    float4 xa = fa[lane + t2 * 64];
    float4 xp = fp[lane + t2 * 64];
    float4 xn = fn[lane + t2 * 64];
    float dp;
    dp = xa.x - xp.x + 1e-6f; sp += dp * dp;
    dp = xa.y - xp.y + 1e-6f; sp += dp * dp;
    dp = xa.z - xp.z + 1e-6f; sp += dp * dp;
    dp = xa.w - xp.w + 1e-6f; sp += dp * dp;
    dp = xa.x - xn.x + 1e-6f; sn += dp * dp;
    dp = xa.y - xn.y + 1e-6f; sn += dp * dp;
    dp = xa.z - xn.z + 1e-6f; sn += dp * dp;
    dp = xa.w - xn.w + 1e-6f; sn += dp * dp;
  }
  sp = wred_sum(sp);
  sn = wred_sum(sn);

  if (lane == 0) {
    float4 qi = apk[i];
    float4 qn = apk[neg];
    float pos_d = sqrtf(sp);
    float neg_d = sqrtf(sn);
    float pa = sqrtf(__uint_as_float((unsigned)(keyP >> 32)));
    float n0 = qi.x - qn.x;
    float n1 = qi.y - qn.y;
    float n2 = qi.z - qn.z;
    float na = sqrtf(n0 * n0 + n1 * n1 + n2 * n2);
    float w = (pa > 45.0f ? 2.0f : 1.0f) * (na < 15.0f ? 1.5f : 1.0f);
    float basic = fmaxf(pos_d - neg_d + 0.2f, 0.0f);
    rowc[i] = w * basic;
    rowv[i] = 1.0f;
  }
}

// ------- Kernel 4: single-block tree reduction + scalar assembly -------
__global__ __launch_bounds__(1024) void k_out(const float* __restrict__ rowc,
                                              const float* __restrict__ rowv,
                                              const float* __restrict__ rowr,
                                              float* __restrict__ out) {
  __shared__ float sc[16], sv[16], sr[16];
  const int t = threadIdx.x;
  float c = 0.0f, v = 0.0f, r = 0.0f;
  for (int i = t; i < BN; i += 1024) {
    c += rowc[i];
    v += rowv[i];
    r += rowr[i];
  }
  c = wred_sum(c);
  v = wred_sum(v);
  r = wred_sum(r);
  const int wid = t >> 6;
  if ((t & 63) == 0) { sc[wid] = c; sv[wid] = v; sr[wid] = r; }
  __syncthreads();
  if (t == 0) {
    float C = 0.0f, V = 0.0f, R = 0.0f;
#pragma unroll
    for (int k = 0; k < 16; k++) { C += sc[k]; V += sv[k]; R += sr[k]; }
    float tri = C / fmaxf(V, 1.0f);
    float recon = 1.0f - R / (float)BN;
    out[0] = tri + 0.1f * recon;
  }
}

extern "C" void kernel_launch(void* const* d_in, const int* in_sizes, int n_in,
                              void* d_out, int out_size, void* d_ws, size_t ws_size,
                              hipStream_t stream) {
  const float* feat = (const float*)d_in[0];
  const int* labels = (const int*)d_in[1];
  const float* angles = (const float*)d_in[2];
  const float* forig = (const float*)d_in[3];
  float* out = (float*)d_out;

  char* ws = (char*)d_ws;
  unsigned short* gb = (unsigned short*)ws;                    // 4 MB bf16 normalized rows
  size_t off = (size_t)BN * FD * sizeof(unsigned short);
  u64* pkey = (u64*)(ws + off);      off += (size_t)NPC * BN * 8;   // 4 MB (S channel)
  u64* pangP = (u64*)(ws + off);     off += (size_t)NJR * BN * 8;   // 1 MB
  u64* pangN = (u64*)(ws + off);     off += (size_t)NJR * BN * 8;   // 1 MB
  float4* apk = (float4*)(ws + off); off += (size_t)BN * 16;        // 64 KB
  float* rowc = (float*)(ws + off);  off += (size_t)BN * 4;
  float* rowv = (float*)(ws + off);  off += (size_t)BN * 4;
  float* rowr = (float*)(ws + off);  off += (size_t)BN * 4;

  k_prep<<<BN / 4, 256, 0, stream>>>(feat, forig, angles, labels, gb, rowr, apk);
  k_sim<<<NBLK + NABLK, 256, 0, stream>>>(gb, apk, pkey, pangP, pangN);
  k_final<<<BN / 4, 256, 0, stream>>>(feat, apk, pkey, pangP, pangN, rowc, rowv);
  k_out<<<1, 1024, 0, stream>>>(rowc, rowv, rowr, out);
}

// Round 8
// 109.399 us; speedup vs baseline: 1.0437x; 1.0437x over previous
//
#include <hip/hip_runtime.h>
#include <math.h>

#define BN 4096
#define FD 512
#define TT 128            // i-tile (rows per block)
#define TJ 64             // j-subtile (cols per block)
#define BK 64             // k-chunk (elements)
#define NJT (BN / TT)     // 32 tiles per dim
#define NPAIR (NJT * (NJT + 1) / 2)   // 528 triangular pairs
#define NBLK (NPAIR * 2)              // 1056 GEMM blocks (j split in halves)
#define NPC 128           // S partial slots per row: col 0..63, row 64..127
#define NJR 32            // angle-pass j-ranges
#define JR (BN / NJR)     // 128 j per range
#define NABLK (NJR * (BN / 256))      // 512 angle blocks (fused into k_sim grid)

typedef __attribute__((ext_vector_type(8))) __bf16 bf16x8;
typedef __attribute__((ext_vector_type(4))) float floatx4;
typedef unsigned long long u64;

__device__ __forceinline__ float wred_sum(float v) {
#pragma unroll
  for (int m = 1; m < 64; m <<= 1) v += __shfl_xor(v, m, 64);
  return v;
}

__device__ __forceinline__ float dot4(float4 a, float4 b) {
  return a.x * b.x + a.y * b.y + a.z * b.z + a.w * b.w;
}

// round-to-nearest-even f32 -> bf16
__device__ __forceinline__ unsigned short f2bf(float x) {
  unsigned u = __float_as_uint(x);
  u += 0x7fffu + ((u >> 16) & 1u);
  return (unsigned short)(u >> 16);
}

__device__ __forceinline__ void load16(const void* g, void* l) {
  __builtin_amdgcn_global_load_lds(
      (const __attribute__((address_space(1))) unsigned int*)g,
      (__attribute__((address_space(3))) unsigned int*)l, 16, 0, 0);
}

// order-preserving float->uint map (monotone for all finite floats)
__device__ __forceinline__ unsigned ford(float v) {
  unsigned u = __float_as_uint(v);
  return u ^ (((unsigned)((int)u >> 31)) | 0x80000000u);
}

// DPP row-rotate (within 16-lane row) — VALU-pipe cross-lane.
template <int N>
__device__ __forceinline__ int rori(int x) {
  return __builtin_amdgcn_update_dpp(0, x, 0x120 | N, 0xf, 0xf, true);
}
template <int N>
__device__ __forceinline__ u64 ror16_u64(u64 k) {
  unsigned lo = (unsigned)rori<N>((int)(unsigned)k);
  unsigned hi = (unsigned)rori<N>((int)(unsigned)(k >> 32));
  return ((u64)hi << 32) | lo;
}
__device__ __forceinline__ u64 red16_max_u64(u64 k) {
  u64 o;
  o = ror16_u64<1>(k); k = o > k ? o : k;
  o = ror16_u64<2>(k); k = o > k ? o : k;
  o = ror16_u64<4>(k); k = o > k ? o : k;
  o = ror16_u64<8>(k); k = o > k ? o : k;
  return k;
}

// 64-lane xor-shuffle on u64 (two 32-bit shuffles)
__device__ __forceinline__ u64 sx64(u64 v, int m) {
  unsigned lo = (unsigned)__shfl_xor((int)(unsigned)v, m, 64);
  unsigned hi = (unsigned)__shfl_xor((int)(unsigned)(v >> 32), m, 64);
  return ((u64)hi << 32) | lo;
}

__device__ __forceinline__ u64 umax64(u64 a, u64 b) { return a > b ? a : b; }

// ------- Kernel 1: normalize rows -> bf16 g, recon cosine, packed angles -----
// apk[t] = {ax, ay, az, label_bits} — one 16B load replaces 4 scalar gathers.
__global__ __launch_bounds__(256) void k_prep(const float* __restrict__ f,
                                              const float* __restrict__ fo,
                                              const float* __restrict__ angles,
                                              const int* __restrict__ labels,
                                              unsigned short* __restrict__ gb,
                                              float* __restrict__ rowr,
                                              float4* __restrict__ apk) {
  const int i = blockIdx.x * 4 + (threadIdx.x >> 6);
  const int lane = threadIdx.x & 63;
  const int t = blockIdx.x * 256 + threadIdx.x;
  if (t < BN) {
    float4 q;
    q.x = angles[t * 3 + 0];
    q.y = angles[t * 3 + 1];
    q.z = angles[t * 3 + 2];
    q.w = __uint_as_float((unsigned)labels[t]);   // bit container only
    apk[t] = q;
  }
  const float4* fr = (const float4*)(f + (size_t)i * FD);
  const float4* orr = (const float4*)(fo + (size_t)i * FD);
  float4 x0 = fr[lane], x1 = fr[lane + 64];
  float4 y0 = orr[lane], y1 = orr[lane + 64];
  float sff = dot4(x0, x0) + dot4(x1, x1);
  float sfo = dot4(x0, y0) + dot4(x1, y1);
  float soo = dot4(y0, y0) + dot4(y1, y1);
  sff = wred_sum(sff);
  sfo = wred_sum(sfo);
  soo = wred_sum(soo);
  float nf = sqrtf(sff);
  float inv = 1.0f / nf;
  ushort4* gr = (ushort4*)(gb + (size_t)i * FD);
  ushort4 s0, s1;
  s0.x = f2bf(x0.x * inv); s0.y = f2bf(x0.y * inv);
  s0.z = f2bf(x0.z * inv); s0.w = f2bf(x0.w * inv);
  s1.x = f2bf(x1.x * inv); s1.y = f2bf(x1.y * inv);
  s1.z = f2bf(x1.z * inv); s1.w = f2bf(x1.w * inv);
  gr[lane] = s0;
  gr[lane + 64] = s1;
  if (lane == 0) {
    rowr[i] = sfo / fmaxf(nf * sqrtf(soo), 1e-8f);
  }
}

// ------- Kernel 2: bf16 MFMA g.gT (S channel) + fused angle P/N pass --------
// Blocks [0, NBLK): 128x64 GEMM (round-0/round-4 structure, best measured),
//   single-channel S epilogue.
// Blocks [NBLK, NBLK+NABLK): angle pass — lane=row (angles in regs), j-range
//   of 128 staged in LDS and read wave-uniform (broadcast, conflict-free).
// P: same-label max angle dist (key = ddbits<<32 | ~j, max, tie->smaller j)
// N: diff-label min angle dist (key = ~(ddbits<<32 | j), max, tie->smaller j)
__global__ __launch_bounds__(256, 4) void k_sim(const unsigned short* __restrict__ gb,
                                                const float4* __restrict__ apk,
                                                u64* __restrict__ pkey,
                                                u64* __restrict__ pangP,
                                                u64* __restrict__ pangN) {
  __shared__ __align__(16) unsigned short As[TT * BK];   // 16 KB
  __shared__ unsigned short Bs[TJ * BK];                 // 8 KB
  const int tid = threadIdx.x;

  if (blockIdx.x >= NBLK) {
    // ---------------- angle P/N pass ----------------
    const int q = blockIdx.x - NBLK;
    const int jr = q & (NJR - 1);      // j-range
    const int ib = q >> 5;             // i-block of 256 rows
    const int i = ib * 256 + tid;
    float4* aj = (float4*)As;          // reuse GEMM LDS (2 KB of 16 KB)
    if (tid < JR) aj[tid] = apk[jr * JR + tid];
    __syncthreads();
    float4 me = apk[i];
    const unsigned lib = __float_as_uint(me.w);
    const int j0 = jr * JR;
    u64 keyP = 0, keyNc = 0;
#pragma unroll 4
    for (int jj = 0; jj < JR; jj++) {
      float4 aw = aj[jj];              // wave-uniform address -> LDS broadcast
      int j = j0 + jj;
      float d0 = me.x - aw.x;
      float d1 = me.y - aw.y;
      float d2 = me.z - aw.z;
      float dd = d0 * d0 + d1 * d1 + d2 * d2;
      u64 ddh = (u64)__float_as_uint(dd) << 32;   // dd>=0: bits monotone
      bool same = (__float_as_uint(aw.w) == lib);
      u64 kp = ddh | (unsigned)(~j);
      if (same && j != i && kp > keyP) keyP = kp;
      u64 kn = ~(ddh | (unsigned)j);
      if (!same && kn > keyNc) keyNc = kn;
    }
    pangP[(size_t)jr * BN + i] = keyP;   // coalesced, fully populated
    pangN[(size_t)jr * BN + i] = keyNc;
    return;
  }

  // ---------------- GEMM + S epilogue (128x64 tile, round-0 structure) ------
  const int h = blockIdx.x & 1;
  int a = 0, rem = blockIdx.x >> 1;
#pragma unroll 1
  while (rem >= NJT - a) { rem -= NJT - a; a++; }
  const int b = a + rem;
  const int i0 = a * TT;
  const int j0 = b * TT + h * TJ;

  const int w = tid >> 6;
  const int lane = tid & 63;

  floatx4 acc[2][4];
#pragma unroll
  for (int u = 0; u < 2; u++)
#pragma unroll
    for (int v = 0; v < 4; v++) acc[u][v] = (floatx4){0.f, 0.f, 0.f, 0.f};

  // Staging: position p = tid + 256c holds row p>>3, logical chunk (p&7)^((p>>3)&7).
  const int rp = tid >> 3;                          // 0..31
  const int q8 = ((tid & 7) ^ (rp & 7)) * 8;        // global chunk offset (elems)
  const unsigned short* gA[4];
  const unsigned short* gB[2];
  unsigned short* lA[4];
  unsigned short* lB[2];
#pragma unroll
  for (int c = 0; c < 4; c++) {
    gA[c] = gb + (size_t)(i0 + rp + 32 * c) * FD + q8;
    lA[c] = As + (tid + 256 * c) * 8;
  }
#pragma unroll
  for (int c = 0; c < 2; c++) {
    gB[c] = gb + (size_t)(j0 + rp + 32 * c) * FD + q8;
    lB[c] = Bs + (tid + 256 * c) * 8;
  }

  // Fragment reads: swizzled chunk position q ^ (lane&7).
  const int m = lane & 15;
  const int arow = w * 32 + m;      // + u*16
  const int brow = m;               // + v*16
  const int g4 = lane >> 4;
  const int l7 = lane & 7;
  const int koff0 = (g4 ^ l7) * 8;
  const int koff1 = ((4 + g4) ^ l7) * 8;

  for (int kc = 0; kc < FD; kc += BK) {
#pragma unroll
    for (int c = 0; c < 4; c++) load16(gA[c] + kc, lA[c]);
#pragma unroll
    for (int c = 0; c < 2; c++) load16(gB[c] + kc, lB[c]);
    __syncthreads();
    bf16x8 af[2], bf[4];
#pragma unroll
    for (int u = 0; u < 2; u++)
      af[u] = *(const bf16x8*)(As + (arow + u * 16) * BK + koff0);
#pragma unroll
    for (int v = 0; v < 4; v++)
      bf[v] = *(const bf16x8*)(Bs + (brow + v * 16) * BK + koff0);
#pragma unroll
    for (int u = 0; u < 2; u++)
#pragma unroll
      for (int v = 0; v < 4; v++)
        acc[u][v] = __builtin_amdgcn_mfma_f32_16x16x32_bf16(af[u], bf[v], acc[u][v], 0, 0, 0);
#pragma unroll
    for (int u = 0; u < 2; u++)
      af[u] = *(const bf16x8*)(As + (arow + u * 16) * BK + koff1);
#pragma unroll
    for (int v = 0; v < 4; v++)
      bf[v] = *(const bf16x8*)(Bs + (brow + v * 16) * BK + koff1);
#pragma unroll
    for (int u = 0; u < 2; u++)
#pragma unroll
      for (int v = 0; v < 4; v++)
        acc[u][v] = __builtin_amdgcn_mfma_f32_16x16x32_bf16(af[u], bf[v], acc[u][v], 0, 0, 0);
    __syncthreads();
  }

  // Epilogue: C layout col=lane&15, row=quad*4+reg (16x16 family).
  const int quad = lane >> 4;
  const int cx = lane & 15;
  int jc[4];
  unsigned ljb[4];
  float jx[4], jy[4], jz[4];
#pragma unroll
  for (int v = 0; v < 4; v++) {
    jc[v] = j0 + v * 16 + cx;
    float4 qj = apk[jc[v]];
    jx[v] = qj.x;
    jy[v] = qj.y;
    jz[v] = qj.z;
    ljb[v] = __float_as_uint(qj.w);
  }
  const size_t rbase = (size_t)(64 + 2 * b + h) * BN;   // row-part slot
  u64 ckey[4] = {0, 0, 0, 0};                           // col-part keys per v
#pragma unroll
  for (int u = 0; u < 2; u++) {
#pragma unroll
    for (int reg = 0; reg < 4; reg++) {
      int i = i0 + w * 32 + u * 16 + quad * 4 + reg;
      float4 qi = apk[i];
      unsigned lib = __float_as_uint(qi.w);
      u64 rkey = 0;
      unsigned ni = (unsigned)(~i);
#pragma unroll
      for (int v = 0; v < 4; v++) {
        float d0 = qi.x - jx[v];
        float d1 = qi.y - jy[v];
        float d2 = qi.z - jz[v];
        float dd = d0 * d0 + d1 * d1 + d2 * d2;
        bool ok = (lib != ljb[v]) && (dd < 900.0f);   // sqrt(dd)<30
        u64 vh = (u64)ford(acc[u][v][reg]) << 32;
        u64 candR = vh | (unsigned)(~jc[v]);
        if (ok && candR > rkey) rkey = candR;
        u64 candC = vh | ni;
        if (ok && candC > ckey[v]) ckey[v] = candC;
      }
      rkey = red16_max_u64(rkey);
      if (cx == 0) pkey[rbase + i] = rkey;
    }
  }
  if (a != b) {
    // per-wave column argmax over this wave's 32 rows: reduce across quads
    const size_t cbase = (size_t)(4 * a + w) * BN;
#pragma unroll
    for (int v = 0; v < 4; v++) {
      u64 k = ckey[v];
      u64 o = sx64(k, 16); if (o > k) k = o;
      o = sx64(k, 32); if (o > k) k = o;
      if (quad == 0) pkey[cbase + jc[v]] = k;
    }
  }
}

// ------- Kernel 3: per-row finalize — S/P/N partial merges + distances ------
// S slots for row i (tile t=i>>7): col slots [0,4t), row slots [64+2t,128).
// P/N: 32 fully-populated partials each; lane<32 merges P, lane>=32 merges N.
__global__ __launch_bounds__(256) void k_final(const float* __restrict__ f,
                                               const float4* __restrict__ apk,
                                               const u64* __restrict__ pkey,
                                               const u64* __restrict__ pangP,
                                               const u64* __restrict__ pangN,
                                               float* __restrict__ rowc,
                                               float* __restrict__ rowv) {
  const int i = blockIdx.x * 4 + (threadIdx.x >> 6);
  const int lane = threadIdx.x & 63;
  const int t = i >> 7;

  // S partials: two slots per lane with stale-slot masks
  u64 s0 = (lane < 4 * t) ? pkey[(size_t)lane * BN + i] : 0;
  u64 s1 = (lane >= 2 * t) ? pkey[(size_t)(64 + lane) * BN + i] : 0;
  u64 keyS = umax64(s0, s1);
  // P/N partials: exactly 32 + 32 across the wave
  u64 keyP = (lane < NJR) ? pangP[(size_t)lane * BN + i] : 0;
  u64 keyNc = (lane >= NJR) ? pangN[(size_t)(lane - NJR) * BN + i] : 0;
#pragma unroll
  for (int off = 1; off < 64; off <<= 1) {
    u64 o = sx64(keyS, off); if (o > keyS) keyS = o;
    o = sx64(keyP, off); if (o > keyP) keyP = o;
    o = sx64(keyNc, off); if (o > keyNc) keyNc = o;
  }
  bool hp = keyP != 0;      // any same-label j != i
  bool hn = keyNc != 0;     // any diff-label j
  if (!(hp && hn)) {
    if (lane == 0) { rowc[i] = 0.0f; rowv[i] = 0.0f; }
    return;
  }
  bool sim_any = keyS != 0;
  int pos = (int)(~(unsigned)keyP);
  u64 keyN = ~keyNc;        // (ddbits<<32 | j) of the min
  int neg = sim_any ? (int)(~(unsigned)keyS) : (int)(unsigned)keyN;

  // triplet distances (reference adds 1e-6 to the per-element difference)
  const float4* fa = (const float4*)(f + (size_t)i * FD);
  const float4* fp = (const float4*)(f + (size_t)pos * FD);
  const float4* fn = (const float4*)(f + (size_t)neg * FD);
  float sp = 0.0f, sn = 0.0f;
#pragma unroll
  for (int t2 = 0; t2 < 2; t2++) {
    float4 xa = fa[lane + t2 * 64];
    float4 xp = fp[lane + t2 * 64];
    float4 xn = fn[lane + t2 * 64];
    float dp;
    dp = xa.x - xp.x + 1e-6f; sp += dp * dp;
    dp = xa.y - xp.y + 1e-6f; sp += dp * dp;
    dp = xa.z - xp.z + 1e-6f; sp += dp * dp;
    dp = xa.w - xp.w + 1e-6f; sp += dp * dp;
    dp = xa.x - xn.x + 1e-6f; sn += dp * dp;
    dp = xa.y - xn.y + 1e-6f; sn += dp * dp;
    dp = xa.z - xn.z + 1e-6f; sn += dp * dp;
    dp = xa.w - xn.w + 1e-6f; sn += dp * dp;
  }
  sp = wred_sum(sp);
  sn = wred_sum(sn);

  if (lane == 0) {
    float4 qi = apk[i];
    float4 qn = apk[neg];
    float pos_d = sqrtf(sp);
    float neg_d = sqrtf(sn);
    float pa = sqrtf(__uint_as_float((unsigned)(keyP >> 32)));
    float n0 = qi.x - qn.x;
    float n1 = qi.y - qn.y;
    float n2 = qi.z - qn.z;
    float na = sqrtf(n0 * n0 + n1 * n1 + n2 * n2);
    float w = (pa > 45.0f ? 2.0f : 1.0f) * (na < 15.0f ? 1.5f : 1.0f);
    float basic = fmaxf(pos_d - neg_d + 0.2f, 0.0f);
    rowc[i] = w * basic;
    rowv[i] = 1.0f;
  }
}

// ------- Kernel 4: single-block tree reduction + scalar assembly -------
__global__ __launch_bounds__(1024) void k_out(const float* __restrict__ rowc,
                                              const float* __restrict__ rowv,
                                              const float* __restrict__ rowr,
                                              float* __restrict__ out) {
  __shared__ float sc[16], sv[16], sr[16];
  const int t = threadIdx.x;
  float c = 0.0f, v = 0.0f, r = 0.0f;
  for (int i = t; i < BN; i += 1024) {
    c += rowc[i];
    v += rowv[i];
    r += rowr[i];
  }
  c = wred_sum(c);
  v = wred_sum(v);
  r = wred_sum(r);
  const int wid = t >> 6;
  if ((t & 63) == 0) { sc[wid] = c; sv[wid] = v; sr[wid] = r; }
  __syncthreads();
  if (t == 0) {
    float C = 0.0f, V = 0.0f, R = 0.0f;
#pragma unroll
    for (int k = 0; k < 16; k++) { C += sc[k]; V += sv[k]; R += sr[k]; }
    float tri = C / fmaxf(V, 1.0f);
    float recon = 1.0f - R / (float)BN;
    out[0] = tri + 0.1f * recon;
  }
}

extern "C" void kernel_launch(void* const* d_in, const int* in_sizes, int n_in,
                              void* d_out, int out_size, void* d_ws, size_t ws_size,
                              hipStream_t stream) {
  const float* feat = (const float*)d_in[0];
  const int* labels = (const int*)d_in[1];
  const float* angles = (const float*)d_in[2];
  const float* forig = (const float*)d_in[3];
  float* out = (float*)d_out;

  char* ws = (char*)d_ws;
  unsigned short* gb = (unsigned short*)ws;                    // 4 MB bf16 normalized rows
  size_t off = (size_t)BN * FD * sizeof(unsigned short);
  u64* pkey = (u64*)(ws + off);      off += (size_t)NPC * BN * 8;   // 4 MB (S channel)
  u64* pangP = (u64*)(ws + off);     off += (size_t)NJR * BN * 8;   // 1 MB
  u64* pangN = (u64*)(ws + off);     off += (size_t)NJR * BN * 8;   // 1 MB
  float4* apk = (float4*)(ws + off); off += (size_t)BN * 16;        // 64 KB
  float* rowc = (float*)(ws + off);  off += (size_t)BN * 4;
  float* rowv = (float*)(ws + off);  off += (size_t)BN * 4;
  float* rowr = (float*)(ws + off);  off += (size_t)BN * 4;

  k_prep<<<BN / 4, 256, 0, stream>>>(feat, forig, angles, labels, gb, rowr, apk);
  k_sim<<<NBLK + NABLK, 256, 0, stream>>>(gb, apk, pkey, pangP, pangN);
  k_final<<<BN / 4, 256, 0, stream>>>(feat, apk, pkey, pangP, pangN, rowc, rowv);
  k_out<<<1, 1024, 0, stream>>>(rowc, rowv, rowr, out);
}